// Round 11
// baseline (110.365 us; speedup 1.0000x reference)
//
#include <hip/hip_runtime.h>

// KPConvInterSO3 via MFMA. N=16000, NB=32, A=4, K=15, CIN=COUT=32.
// Block = 256 threads = 4 waves; block handles 4 queries; wave w owns anchor w
// for GEMM1. GEMM2: A rows = 16 (anchor,query) pairs, split across waves by
// (d-tile, kk-range): 32 MFMA + 32 Wp loads per BLOCK + 2KB cross-wave reduce.
// R11: gather uses 8x uint4 (16B/lane) instead of 16x uint2 — lane remap
// (q, bg, ah, cs): 4 rows x 2 adjacent anchors (2nd anchor = +64B instr
// offset), channels cs*8..cs*8+7. Perm/LDS-write volume unchanged; GEMM1
// read mapping unchanged.
// Influence weights via cross-MFMA with bf16 hi/lo split (fp32-grade sq).
// x pre-converted to bf16 (4 MB, L2-resident); W pre-permuted to B-frag layout.

typedef short bf16x8 __attribute__((ext_vector_type(8)));
typedef float f32x4  __attribute__((ext_vector_type(4)));

// round-half-up bf16: 2 VALU ops. <=1 ulp vs RNE on ties.
__device__ __forceinline__ unsigned short f2bf(float f) {
    unsigned u = __builtin_bit_cast(unsigned, f);
    return (unsigned short)((u + 0x8000u) >> 16);
}
__device__ __forceinline__ float bf2f(unsigned short h) {
    return __builtin_bit_cast(float, (unsigned)h << 16);
}
// pack two floats -> (bf(hi)<<16)|bf(lo) in 3 VALU ops via v_perm_b32
__device__ __forceinline__ unsigned pack2bf(float hi, float lo) {
    unsigned uh = __builtin_bit_cast(unsigned, hi) + 0x8000u;
    unsigned ul = __builtin_bit_cast(unsigned, lo) + 0x8000u;
    return __builtin_amdgcn_perm(uh, ul, 0x07060302u);
}
// hi/lo split: v ~= bf(h) + bf(l), residual ~2^-18 rel
__device__ __forceinline__ void bfsplit(float v, unsigned short& h, unsigned short& l) {
    h = f2bf(v);
    l = f2bf(v - bf2f(h));
}

// Combined prep: blocks 0..63 build Wp (W permuted to GEMM2 B-frag layout,
// Wp[kk][d][e] = bf16(W[k][c][d]), kcs = kk*32+e = c*16+k, k=15 -> 0);
// blocks 64..1063 convert x (fp32) -> xb (bf16), 8 floats/thread.
__global__ void prep_all(const float* __restrict__ W, unsigned short* __restrict__ Wp,
                         const float* __restrict__ x, unsigned short* __restrict__ xb) {
    const int bid = blockIdx.x;
    if (bid < 64) {
        const int idx = bid * 256 + threadIdx.x;   // 0..16383
        const int kk = idx >> 10, d = (idx >> 5) & 31, e = idx & 31;
        const int kcs = kk * 32 + e;
        const int c = kcs >> 4, k = kcs & 15;
        const float v = (k < 15) ? W[(k * 32 + c) * 32 + d] : 0.0f;
        Wp[idx] = f2bf(v);
    } else {
        const int i = ((bid - 64) * 256 + threadIdx.x) * 8;
        const float4 v0 = *(const float4*)&x[i];
        const float4 v1 = *(const float4*)&x[i + 4];
        uint4 u;
        u.x = pack2bf(v0.y, v0.x); u.y = pack2bf(v0.w, v0.z);
        u.z = pack2bf(v1.y, v1.x); u.w = pack2bf(v1.w, v1.z);
        *(uint4*)&xb[i] = u;
    }
}

__global__ __launch_bounds__(256) void kpconv_mfma(
    const float* __restrict__ q_pts,    // [N,3]
    const float* __restrict__ s_pts,    // [M,3]
    const int*   __restrict__ inds,     // [N,32]
    const unsigned short* __restrict__ xb, // [M,4,32] bf16
    const float* __restrict__ kp,       // [15,3]
    const float* __restrict__ anchors,  // [4,3,3]
    const unsigned short* __restrict__ Wp, // [16][32][32] bf16 (permuted)
    float*       __restrict__ out)      // [N,4,32]
{
    // xa_s: [a][q][c][b_slot] bf16, 32KB; per-a 4KB slice aliased by wf after
    // GEMM1 (wave-private until barrier 2; additive column shift q*16+a*8).
    __shared__ __align__(16) unsigned short xa_s[16384];
    // nbr32: per (q,b) 16-slot bf16 A-row for the cross-MFMA; row stride 24
    // shorts (48B, keeps 16B alignment). 6 KB. Aliased by red4 after barrier 2.
    __shared__ __align__(16) unsigned short nbr32[3072];

    const int t  = threadIdx.x;
    const int n0 = blockIdx.x * 4;
    const int a = t >> 6, lane = t & 63, l15 = lane & 15, quad = lane >> 4;

    // ---- GEMM2 role constants + hoisted Wp B-frags (independent loads) ----
    const int tile = a & 1;            // d-tile (0: d<16, 1: d>=16)
    const int kkb  = (a >> 1) * 8;     // kk-range
    bf16x8 wreg[8];
    #pragma unroll
    for (int kk2 = 0; kk2 < 8; ++kk2) {
        wreg[kk2] = *(const bf16x8*)&Wp[(kkb + kk2) * 1024 + (tile * 16 + l15) * 32 + quad * 8];
    }

    // ---- prologue: per-lane B-frag (constant) for the cross-MFMA ----
    // kdim slots: 0:k2h 1:k2l 2:Rxh 3:Rxl 4:Rxh 5:Ryh 6:Ryl 7:Ryh |
    //             8:Rzh 9:Rzl 10:Rzh 11:1 12:1 13..31:0    (R = -2*r)
    bf16x8 rkb;
    {
        float rx = 0.f, ry = 0.f, rz = 0.f, k2 = 1e30f;   // k=15 sentinel -> w=0
        if (l15 < 15) {
            const float kx = kp[l15*3+0], ky = kp[l15*3+1], kz = kp[l15*3+2];
            const float* R = anchors + a * 9;
            rx = R[0]*kx + R[1]*ky + R[2]*kz;
            ry = R[3]*kx + R[4]*ky + R[5]*kz;
            rz = R[6]*kx + R[7]*ky + R[8]*kz;
            k2 = rx*rx + ry*ry + rz*rz;
        }
        unsigned short k2h,k2l, Rxh,Rxl, Ryh,Ryl, Rzh,Rzl;
        bfsplit(k2, k2h, k2l);
        bfsplit(-2.0f*rx, Rxh, Rxl);
        bfsplit(-2.0f*ry, Ryh, Ryl);
        bfsplit(-2.0f*rz, Rzh, Rzl);
        const unsigned ONE = 0x3F80u;
        uint4 u;
        if (quad == 0) {
            u.x = (unsigned)k2h | ((unsigned)k2l << 16);
            u.y = (unsigned)Rxh | ((unsigned)Rxl << 16);
            u.z = (unsigned)Rxh | ((unsigned)Ryh << 16);
            u.w = (unsigned)Ryl | ((unsigned)Ryh << 16);
        } else if (quad == 1) {
            u.x = (unsigned)Rzh | ((unsigned)Rzl << 16);
            u.y = (unsigned)Rzh | (ONE << 16);
            u.z = ONE;
            u.w = 0u;
        } else {
            u.x = u.y = u.z = u.w = 0u;   // B slots 16..31 zero -> A there don't-care
        }
        rkb = __builtin_bit_cast(bf16x8, u);
    }

    // ---- P2: gather xb -> xa_s (register transpose), 16B/lane loads ----
    // lane (q = t>>6, bg = (t>>3)&7, ah = (t>>2)&1, cs = t&3):
    // loads 4 rows x anchors {2ah, 2ah+1} x channels cs*8..cs*8+7 (uint4).
    // slot(b=4*bg+i, c) = ((bg&3) ^ ((c>>2)&3))*8 + (bg>>2)*4 + i.
    {
        const int cs = t & 3, ah = (t >> 2) & 1, bg = (t >> 3) & 7, q = t >> 6;
        const int4 rows = *(const int4*)&inds[(n0 + q) * 32 + 4 * bg];
        const unsigned short* g0 = &xb[rows.x * 128 + (ah * 2) * 32 + cs * 8];
        const unsigned short* g1 = &xb[rows.y * 128 + (ah * 2) * 32 + cs * 8];
        const unsigned short* g2 = &xb[rows.z * 128 + (ah * 2) * 32 + cs * 8];
        const unsigned short* g3 = &xb[rows.w * 128 + (ah * 2) * 32 + cs * 8];
        uint4 ra[4], rb[4];
        ra[0] = *(const uint4*)g0;  rb[0] = *(const uint4*)(g0 + 32);
        ra[1] = *(const uint4*)g1;  rb[1] = *(const uint4*)(g1 + 32);
        ra[2] = *(const uint4*)g2;  rb[2] = *(const uint4*)(g2 + 32);
        ra[3] = *(const uint4*)g3;  rb[3] = *(const uint4*)(g3 + 32);

        const int fcA = (cs * 2) & 3, fcB = (cs * 2 + 1) & 3;
        const int slotA = ((bg & 3) ^ fcA) * 8 + (bg >> 2) * 4;
        const int slotB = ((bg & 3) ^ fcB) * 8 + (bg >> 2) * 4;
        #pragma unroll
        for (int aa = 0; aa < 2; ++aa) {
            const uint4* R = aa ? rb : ra;
            const int a2 = ah * 2 + aa;
            unsigned short* pa = &xa_s[((a2 * 4 + q) * 32 + cs * 8) * 32];
            #pragma unroll
            for (int d = 0; d < 4; ++d) {
                const unsigned rr0 = (&R[0].x)[d], rr1 = (&R[1].x)[d];
                const unsigned rr2 = (&R[2].x)[d], rr3 = (&R[3].x)[d];
                const int slot = (d < 2) ? slotA : slotB;
                uint2 w;
                w.x = __builtin_amdgcn_perm(rr1, rr0, 0x05040100u);
                w.y = __builtin_amdgcn_perm(rr3, rr2, 0x05040100u);
                *(uint2*)&pa[(2 * d) * 32 + slot] = w;
                w.x = __builtin_amdgcn_perm(rr1, rr0, 0x07060302u);
                w.y = __builtin_amdgcn_perm(rr3, rr2, 0x07060302u);
                *(uint2*)&pa[(2 * d + 1) * 32 + slot] = w;
            }
        }
    }

    // ---- stage nbr32 A-rows (t<128) ----
    if (t < 128) {
        const int q = t >> 5, b = t & 31;
        const int idx = inds[(n0 + q) * 32 + b];
        const float nx = s_pts[idx*3+0] - q_pts[(n0+q)*3+0];
        const float ny = s_pts[idx*3+1] - q_pts[(n0+q)*3+1];
        const float nz = s_pts[idx*3+2] - q_pts[(n0+q)*3+2];
        const float n2 = nx*nx + ny*ny + nz*nz;
        unsigned short nxh,nxl, nyh,nyl, nzh,nzl, n2h,n2l;
        bfsplit(nx, nxh, nxl); bfsplit(ny, nyh, nyl);
        bfsplit(nz, nzh, nzl); bfsplit(n2, n2h, n2l);
        const unsigned ONE = 0x3F80u;
        // A slots: 0:1 1:1 2:nxh 3:nxh 4:nxl 5:nyh 6:nyh 7:nyl |
        //          8:nzh 9:nzh 10:nzl 11:n2h 12:n2l 13..15:0
        unsigned short* p = &nbr32[(q * 32 + b) * 24];
        *(uint2*)(p)      = make_uint2(ONE | (ONE << 16),
                                       (unsigned)nxh | ((unsigned)nxh << 16));
        *(uint2*)(p + 4)  = make_uint2((unsigned)nxl | ((unsigned)nyh << 16),
                                       (unsigned)nyh | ((unsigned)nyl << 16));
        *(uint2*)(p + 8)  = make_uint2((unsigned)nzh | ((unsigned)nzh << 16),
                                       (unsigned)nzl | ((unsigned)n2h << 16));
        *(uint2*)(p + 12) = make_uint2((unsigned)n2l, 0u);
    }
    __syncthreads();   // barrier 1: xa_s + nbr32 visible

    // ---------------- GEMM1 per wave (anchor a = wave id) ----------------
    const int fc = (l15 >> 2) & 3;
    unsigned short* wfb = &xa_s[a * 4096];
    const f32x4 zacc = {0.f, 0.f, 0.f, 0.f};
    const int S = a * 8;   // + q*16 added per q below (additive column shift)

    #pragma unroll
    for (int q = 0; q < 4; ++q) {
        // cross-MFMA: sq[b][k]; quads 2-3 broadcast quads 0-1 addresses
        // (their B slots are zero -> A values are don't-care).
        const unsigned short* aX = &nbr32[(q * 32 + l15) * 24 + (quad & 1) * 8];
        const unsigned short* aY = &nbr32[(q * 32 + 16 + l15) * 24 + (quad & 1) * 8];
        const f32x4 s0 = __builtin_amdgcn_mfma_f32_16x16x32_bf16(*(const bf16x8*)aX, rkb, zacc, 0, 0, 0);
        const f32x4 s1 = __builtin_amdgcn_mfma_f32_16x16x32_bf16(*(const bf16x8*)aY, rkb, zacc, 0, 0, 0);
        // D: col k = l15, rows b = quad*4+reg (s0), 16+quad*4+reg (s1)
        float w8[8];
        #pragma unroll
        for (int j = 0; j < 4; ++j) {
            w8[j]     = fmaxf(fmaf(sqrtf(fmaxf(s0[j], 1e-12f)), -1.6666667f, 1.0f), 0.0f);
            w8[4 + j] = fmaxf(fmaf(sqrtf(fmaxf(s1[j], 1e-12f)), -1.6666667f, 1.0f), 0.0f);
        }
        uint4 uu;
        uu.x = pack2bf(w8[1], w8[0]); uu.y = pack2bf(w8[3], w8[2]);
        uu.z = pack2bf(w8[5], w8[4]); uu.w = pack2bf(w8[7], w8[6]);
        const bf16x8 afr = __builtin_bit_cast(bf16x8, uu);   // A[k=l15][b-octet(quad)]

        // GEMM1: B[b][c] from xa (slot-permuted to match), D: col c, rows k.
        const bf16x8 b0 = *(const bf16x8*)&xa_s[((a*4 + q)*32 + l15)      * 32 + 8 * (quad ^ fc)];
        const bf16x8 b1 = *(const bf16x8*)&xa_s[((a*4 + q)*32 + l15 + 16) * 32 + 8 * (quad ^ fc)];
        f32x4 d0 = zacc, d1 = zacc;
        d0 = __builtin_amdgcn_mfma_f32_16x16x32_bf16(afr, b0, d0, 0, 0, 0);
        d1 = __builtin_amdgcn_mfma_f32_16x16x32_bf16(afr, b1, d1, 0, 0, 0);
        // wf store: row q, column (kcs + q*16 + a*8) & 511, kcs = c*16 + k
        uint2 s0p, s1p;
        s0p.x = pack2bf(d0[1], d0[0]); s0p.y = pack2bf(d0[3], d0[2]);
        s1p.x = pack2bf(d1[1], d1[0]); s1p.y = pack2bf(d1[3], d1[2]);
        const int Sq = S + q * 16;
        *(uint2*)&wfb[q*512 + ((l15*16       + quad*4 + Sq) & 511)] = s0p;
        *(uint2*)&wfb[q*512 + ((l15*16 + 256 + quad*4 + Sq) & 511)] = s1p;
    }
    __syncthreads();   // barrier 2: all wf visible; also orders nbr32 reads
                       // before the red4 writes below (no extra barrier needed)

    // ---------------- GEMM2 (block-wide, split across waves) ----------------
    // A rows m = a_src*4 + q (16 rows); wave w: d-tile = w&1, kk-range (w>>1)*8.
    const int a_src = l15 >> 2, qv = l15 & 3;
    const unsigned short* abase = &xa_s[a_src * 4096 + qv * 512];
    const int shf = qv * 16 + a_src * 8;
    f32x4 o = zacc;
    #pragma unroll
    for (int kk2 = 0; kk2 < 8; ++kk2) {
        const bf16x8 a2 = *(const bf16x8*)&abase[((kkb + kk2)*32 + quad*8 + shf) & 511];
        o = __builtin_amdgcn_mfma_f32_16x16x32_bf16(a2, wreg[kk2], o, 0, 0, 0);
    }
    // red4 aliases nbr32 — safe: all nbr32 reads were before barrier 2.
    float4* red4 = (float4*)nbr32;   // 2 KB used
    if (a >= 2) {
        red4[(a - 2) * 64 + lane] = make_float4(o[0], o[1], o[2], o[3]);
    }
    __syncthreads();   // partials visible
    if (a < 2) {
        const float4 p = red4[a * 64 + lane];
        o[0] += p.x; o[1] += p.y; o[2] += p.z; o[3] += p.w;
        // D rows m = quad*4+reg -> (a_out = quad, q_out = reg); col d = tile*16+l15
        #pragma unroll
        for (int r = 0; r < 4; ++r) {
            out[((n0 + r) * 4 + quad) * 32 + tile * 16 + l15] = o[r];
        }
    }
}

extern "C" void kernel_launch(void* const* d_in, const int* in_sizes, int n_in,
                              void* d_out, int out_size, void* d_ws, size_t ws_size,
                              hipStream_t stream) {
    const float* q_pts   = (const float*)d_in[0];
    const float* s_pts   = (const float*)d_in[1];
    const int*   inds    = (const int*)d_in[2];
    const float* x       = (const float*)d_in[3];
    const float* kp      = (const float*)d_in[4];
    const float* anchors = (const float*)d_in[5];
    const float* weights = (const float*)d_in[6];
    float*       out     = (float*)d_out;

    unsigned short* Wp = (unsigned short*)d_ws;                       // 32 KB
    unsigned short* xb = (unsigned short*)((char*)d_ws + (1 << 16));  // 4 MB

    prep_all<<<dim3(1064), dim3(256), 0, stream>>>(weights, Wp, x, xb);
    kpconv_mfma<<<dim3(4000), dim3(256), 0, stream>>>(
        q_pts, s_pts, inds, xb, kp, anchors, Wp, out);
}

// Round 12
// 110.129 us; speedup vs baseline: 1.0021x; 1.0021x over previous
//
#include <hip/hip_runtime.h>

// KPConvInterSO3 via MFMA. N=16000, NB=32, A=4, K=15, CIN=COUT=32.
// Block = 256 threads = 4 waves; block handles 4 queries; wave w owns anchor w
// for GEMM1. R12: GEMM2 done by waves 0-1 only, FULL K=16 per wave (d-tile =
// wave id), two interleaved accumulators; waves 2-3 retire after GEMM1.
// Removes the cross-wave LDS reduction + 3rd barrier (2 barriers total).
// Influence weights via cross-MFMA with bf16 hi/lo split (fp32-grade sq).
// x pre-converted to bf16 (4 MB, L2-resident); W pre-permuted to B-frag layout.

typedef short bf16x8 __attribute__((ext_vector_type(8)));
typedef float f32x4  __attribute__((ext_vector_type(4)));

// round-half-up bf16: 2 VALU ops. <=1 ulp vs RNE on ties.
__device__ __forceinline__ unsigned short f2bf(float f) {
    unsigned u = __builtin_bit_cast(unsigned, f);
    return (unsigned short)((u + 0x8000u) >> 16);
}
__device__ __forceinline__ float bf2f(unsigned short h) {
    return __builtin_bit_cast(float, (unsigned)h << 16);
}
// pack two floats -> (bf(hi)<<16)|bf(lo) in 3 VALU ops via v_perm_b32
__device__ __forceinline__ unsigned pack2bf(float hi, float lo) {
    unsigned uh = __builtin_bit_cast(unsigned, hi) + 0x8000u;
    unsigned ul = __builtin_bit_cast(unsigned, lo) + 0x8000u;
    return __builtin_amdgcn_perm(uh, ul, 0x07060302u);
}
// hi/lo split: v ~= bf(h) + bf(l), residual ~2^-18 rel
__device__ __forceinline__ void bfsplit(float v, unsigned short& h, unsigned short& l) {
    h = f2bf(v);
    l = f2bf(v - bf2f(h));
}

// Combined prep: blocks 0..63 build Wp (W permuted to GEMM2 B-frag layout,
// Wp[kk][d][e] = bf16(W[k][c][d]), kcs = kk*32+e = c*16+k, k=15 -> 0);
// blocks 64..1063 convert x (fp32) -> xb (bf16), 8 floats/thread.
__global__ void prep_all(const float* __restrict__ W, unsigned short* __restrict__ Wp,
                         const float* __restrict__ x, unsigned short* __restrict__ xb) {
    const int bid = blockIdx.x;
    if (bid < 64) {
        const int idx = bid * 256 + threadIdx.x;   // 0..16383
        const int kk = idx >> 10, d = (idx >> 5) & 31, e = idx & 31;
        const int kcs = kk * 32 + e;
        const int c = kcs >> 4, k = kcs & 15;
        const float v = (k < 15) ? W[(k * 32 + c) * 32 + d] : 0.0f;
        Wp[idx] = f2bf(v);
    } else {
        const int i = ((bid - 64) * 256 + threadIdx.x) * 8;
        const float4 v0 = *(const float4*)&x[i];
        const float4 v1 = *(const float4*)&x[i + 4];
        uint4 u;
        u.x = pack2bf(v0.y, v0.x); u.y = pack2bf(v0.w, v0.z);
        u.z = pack2bf(v1.y, v1.x); u.w = pack2bf(v1.w, v1.z);
        *(uint4*)&xb[i] = u;
    }
}

__global__ __launch_bounds__(256) void kpconv_mfma(
    const float* __restrict__ q_pts,    // [N,3]
    const float* __restrict__ s_pts,    // [M,3]
    const int*   __restrict__ inds,     // [N,32]
    const unsigned short* __restrict__ xb, // [M,4,32] bf16
    const float* __restrict__ kp,       // [15,3]
    const float* __restrict__ anchors,  // [4,3,3]
    const unsigned short* __restrict__ Wp, // [16][32][32] bf16 (permuted)
    float*       __restrict__ out)      // [N,4,32]
{
    // xa_s: [a][q][c][b_slot] bf16, 32KB; per-a 4KB slice aliased by wf after
    // GEMM1 (wave-private until barrier 2; additive column shift q*16+a*8).
    __shared__ __align__(16) unsigned short xa_s[16384];
    // nbr32: per (q,b) 16-slot bf16 A-row for the cross-MFMA; row stride 24
    // shorts (48B, keeps 16B alignment). 6 KB.
    __shared__ __align__(16) unsigned short nbr32[3072];

    const int t  = threadIdx.x;
    const int n0 = blockIdx.x * 4;
    const int a = t >> 6, lane = t & 63, l15 = lane & 15, quad = lane >> 4;

    // ---- GEMM2 role: waves 0-1 only, d-tile = wave id, full K ----
    const int tile = a & 1;
    bf16x8 wreg[16];
    if (a < 2) {
        #pragma unroll
        for (int kk = 0; kk < 16; ++kk) {
            wreg[kk] = *(const bf16x8*)&Wp[kk * 1024 + (tile * 16 + l15) * 32 + quad * 8];
        }
    }

    // ---- prologue: per-lane B-frag (constant) for the cross-MFMA ----
    // kdim slots: 0:k2h 1:k2l 2:Rxh 3:Rxl 4:Rxh 5:Ryh 6:Ryl 7:Ryh |
    //             8:Rzh 9:Rzl 10:Rzh 11:1 12:1 13..31:0    (R = -2*r)
    bf16x8 rkb;
    {
        float rx = 0.f, ry = 0.f, rz = 0.f, k2 = 1e30f;   // k=15 sentinel -> w=0
        if (l15 < 15) {
            const float kx = kp[l15*3+0], ky = kp[l15*3+1], kz = kp[l15*3+2];
            const float* R = anchors + a * 9;
            rx = R[0]*kx + R[1]*ky + R[2]*kz;
            ry = R[3]*kx + R[4]*ky + R[5]*kz;
            rz = R[6]*kx + R[7]*ky + R[8]*kz;
            k2 = rx*rx + ry*ry + rz*rz;
        }
        unsigned short k2h,k2l, Rxh,Rxl, Ryh,Ryl, Rzh,Rzl;
        bfsplit(k2, k2h, k2l);
        bfsplit(-2.0f*rx, Rxh, Rxl);
        bfsplit(-2.0f*ry, Ryh, Ryl);
        bfsplit(-2.0f*rz, Rzh, Rzl);
        const unsigned ONE = 0x3F80u;
        uint4 u;
        if (quad == 0) {
            u.x = (unsigned)k2h | ((unsigned)k2l << 16);
            u.y = (unsigned)Rxh | ((unsigned)Rxl << 16);
            u.z = (unsigned)Rxh | ((unsigned)Ryh << 16);
            u.w = (unsigned)Ryl | ((unsigned)Ryh << 16);
        } else if (quad == 1) {
            u.x = (unsigned)Rzh | ((unsigned)Rzl << 16);
            u.y = (unsigned)Rzh | (ONE << 16);
            u.z = ONE;
            u.w = 0u;
        } else {
            u.x = u.y = u.z = u.w = 0u;   // B slots 16..31 zero -> A there don't-care
        }
        rkb = __builtin_bit_cast(bf16x8, u);
    }

    // ---- stage nbr32 A-rows (t<128) ----
    if (t < 128) {
        const int q = t >> 5, b = t & 31;
        const int idx = inds[(n0 + q) * 32 + b];
        const float nx = s_pts[idx*3+0] - q_pts[(n0+q)*3+0];
        const float ny = s_pts[idx*3+1] - q_pts[(n0+q)*3+1];
        const float nz = s_pts[idx*3+2] - q_pts[(n0+q)*3+2];
        const float n2 = nx*nx + ny*ny + nz*nz;
        unsigned short nxh,nxl, nyh,nyl, nzh,nzl, n2h,n2l;
        bfsplit(nx, nxh, nxl); bfsplit(ny, nyh, nyl);
        bfsplit(nz, nzh, nzl); bfsplit(n2, n2h, n2l);
        const unsigned ONE = 0x3F80u;
        // A slots: 0:1 1:1 2:nxh 3:nxh 4:nxl 5:nyh 6:nyh 7:nyl |
        //          8:nzh 9:nzh 10:nzl 11:n2h 12:n2l 13..15:0
        unsigned short* p = &nbr32[(q * 32 + b) * 24];
        *(uint2*)(p)      = make_uint2(ONE | (ONE << 16),
                                       (unsigned)nxh | ((unsigned)nxh << 16));
        *(uint2*)(p + 4)  = make_uint2((unsigned)nxl | ((unsigned)nyh << 16),
                                       (unsigned)nyh | ((unsigned)nyl << 16));
        *(uint2*)(p + 8)  = make_uint2((unsigned)nzh | ((unsigned)nzh << 16),
                                       (unsigned)nzl | ((unsigned)n2h << 16));
        *(uint2*)(p + 12) = make_uint2((unsigned)n2l, 0u);
    }

    // ---- P2: gather xb -> xa_s (register transpose) ----
    // logical b = 4*bg+i -> slot = ((bg&3)^fc)*8 + (bg>>2)*4 + i, fc = c4&3.
    {
        const int c4 = t & 7, bg = (t >> 3) & 7, q = t >> 6;
        const int4 rows = *(const int4*)&inds[(n0 + q) * 32 + 4 * bg];
        const int fcs   = c4 & 3;
        const int slotb = ((bg & 3) ^ fcs) * 8 + (bg >> 2) * 4;
        unsigned short* base = &xa_s[(q * 32) * 32 + slotb];
        #pragma unroll
        for (int aa = 0; aa < 4; ++aa) {
            const uint2 r0 = *(const uint2*)&xb[rows.x * 128 + aa * 32 + c4 * 4];
            const uint2 r1 = *(const uint2*)&xb[rows.y * 128 + aa * 32 + c4 * 4];
            const uint2 r2 = *(const uint2*)&xb[rows.z * 128 + aa * 32 + c4 * 4];
            const uint2 r3 = *(const uint2*)&xb[rows.w * 128 + aa * 32 + c4 * 4];
            unsigned short* pa = base + aa * 4096;
            uint2 w;
            w.x = __builtin_amdgcn_perm(r1.x, r0.x, 0x05040100u);
            w.y = __builtin_amdgcn_perm(r3.x, r2.x, 0x05040100u);
            *(uint2*)&pa[(4 * c4 + 0) * 32] = w;
            w.x = __builtin_amdgcn_perm(r1.x, r0.x, 0x07060302u);
            w.y = __builtin_amdgcn_perm(r3.x, r2.x, 0x07060302u);
            *(uint2*)&pa[(4 * c4 + 1) * 32] = w;
            w.x = __builtin_amdgcn_perm(r1.y, r0.y, 0x05040100u);
            w.y = __builtin_amdgcn_perm(r3.y, r2.y, 0x05040100u);
            *(uint2*)&pa[(4 * c4 + 2) * 32] = w;
            w.x = __builtin_amdgcn_perm(r1.y, r0.y, 0x07060302u);
            w.y = __builtin_amdgcn_perm(r3.y, r2.y, 0x07060302u);
            *(uint2*)&pa[(4 * c4 + 3) * 32] = w;
        }
    }
    __syncthreads();   // barrier 1: xa_s + nbr32 visible

    // ---------------- GEMM1 per wave (anchor a = wave id) ----------------
    const int fc = (l15 >> 2) & 3;
    unsigned short* wfb = &xa_s[a * 4096];
    const f32x4 zacc = {0.f, 0.f, 0.f, 0.f};
    const int S = a * 8;   // + q*16 added per q below (additive column shift)

    #pragma unroll
    for (int q = 0; q < 4; ++q) {
        // cross-MFMA: sq[b][k]; quads 2-3 broadcast quads 0-1 addresses
        // (their B slots are zero -> A values are don't-care).
        const unsigned short* aX = &nbr32[(q * 32 + l15) * 24 + (quad & 1) * 8];
        const unsigned short* aY = &nbr32[(q * 32 + 16 + l15) * 24 + (quad & 1) * 8];
        const f32x4 s0 = __builtin_amdgcn_mfma_f32_16x16x32_bf16(*(const bf16x8*)aX, rkb, zacc, 0, 0, 0);
        const f32x4 s1 = __builtin_amdgcn_mfma_f32_16x16x32_bf16(*(const bf16x8*)aY, rkb, zacc, 0, 0, 0);
        // D: col k = l15, rows b = quad*4+reg (s0), 16+quad*4+reg (s1)
        float w8[8];
        #pragma unroll
        for (int j = 0; j < 4; ++j) {
            w8[j]     = fmaxf(fmaf(sqrtf(fmaxf(s0[j], 1e-12f)), -1.6666667f, 1.0f), 0.0f);
            w8[4 + j] = fmaxf(fmaf(sqrtf(fmaxf(s1[j], 1e-12f)), -1.6666667f, 1.0f), 0.0f);
        }
        uint4 uu;
        uu.x = pack2bf(w8[1], w8[0]); uu.y = pack2bf(w8[3], w8[2]);
        uu.z = pack2bf(w8[5], w8[4]); uu.w = pack2bf(w8[7], w8[6]);
        const bf16x8 afr = __builtin_bit_cast(bf16x8, uu);   // A[k=l15][b-octet(quad)]

        // GEMM1: B[b][c] from xa (slot-permuted to match), D: col c, rows k.
        const bf16x8 b0 = *(const bf16x8*)&xa_s[((a*4 + q)*32 + l15)      * 32 + 8 * (quad ^ fc)];
        const bf16x8 b1 = *(const bf16x8*)&xa_s[((a*4 + q)*32 + l15 + 16) * 32 + 8 * (quad ^ fc)];
        f32x4 d0 = zacc, d1 = zacc;
        d0 = __builtin_amdgcn_mfma_f32_16x16x32_bf16(afr, b0, d0, 0, 0, 0);
        d1 = __builtin_amdgcn_mfma_f32_16x16x32_bf16(afr, b1, d1, 0, 0, 0);
        // wf store: row q, column (kcs + q*16 + a*8) & 511, kcs = c*16 + k
        uint2 s0p, s1p;
        s0p.x = pack2bf(d0[1], d0[0]); s0p.y = pack2bf(d0[3], d0[2]);
        s1p.x = pack2bf(d1[1], d1[0]); s1p.y = pack2bf(d1[3], d1[2]);
        const int Sq = S + q * 16;
        *(uint2*)&wfb[q*512 + ((l15*16       + quad*4 + Sq) & 511)] = s0p;
        *(uint2*)&wfb[q*512 + ((l15*16 + 256 + quad*4 + Sq) & 511)] = s1p;
    }
    __syncthreads();   // barrier 2: all wf visible to waves 0-1

    // ---------------- GEMM2 (waves 0-1, full K, no cross-wave reduce) ------
    // A rows m = a_src*4 + qv (16 rows); wave w (w<2): d-tile = w, kk = 0..15.
    if (a < 2) {
        const int a_src = l15 >> 2, qv = l15 & 3;
        const unsigned short* abase = &xa_s[a_src * 4096 + qv * 512];
        const int shf = qv * 16 + a_src * 8;
        f32x4 oe = zacc, oo = zacc;   // two accumulators break the dep chain
        #pragma unroll
        for (int kk = 0; kk < 16; kk += 2) {
            const bf16x8 a0 = *(const bf16x8*)&abase[( kk     *32 + quad*8 + shf) & 511];
            const bf16x8 a1 = *(const bf16x8*)&abase[((kk + 1)*32 + quad*8 + shf) & 511];
            oe = __builtin_amdgcn_mfma_f32_16x16x32_bf16(a0, wreg[kk],     oe, 0, 0, 0);
            oo = __builtin_amdgcn_mfma_f32_16x16x32_bf16(a1, wreg[kk + 1], oo, 0, 0, 0);
        }
        // D rows m = quad*4+reg -> (a_out = quad, q_out = reg); col d = tile*16+l15
        #pragma unroll
        for (int r = 0; r < 4; ++r) {
            out[((n0 + r) * 4 + quad) * 32 + tile * 16 + l15] = oe[r] + oo[r];
        }
    }
    // waves 2-3 retire here
}

extern "C" void kernel_launch(void* const* d_in, const int* in_sizes, int n_in,
                              void* d_out, int out_size, void* d_ws, size_t ws_size,
                              hipStream_t stream) {
    const float* q_pts   = (const float*)d_in[0];
    const float* s_pts   = (const float*)d_in[1];
    const int*   inds    = (const int*)d_in[2];
    const float* x       = (const float*)d_in[3];
    const float* kp      = (const float*)d_in[4];
    const float* anchors = (const float*)d_in[5];
    const float* weights = (const float*)d_in[6];
    float*       out     = (float*)d_out;

    unsigned short* Wp = (unsigned short*)d_ws;                       // 32 KB
    unsigned short* xb = (unsigned short*)((char*)d_ws + (1 << 16));  // 4 MB

    prep_all<<<dim3(1064), dim3(256), 0, stream>>>(weights, Wp, x, xb);
    kpconv_mfma<<<dim3(4000), dim3(256), 0, stream>>>(
        q_pts, s_pts, inds, xb, kp, anchors, Wp, out);
}

// Round 13
// 109.273 us; speedup vs baseline: 1.0100x; 1.0078x over previous
//
#include <hip/hip_runtime.h>

// KPConvInterSO3 via MFMA. N=16000, NB=32, A=4, K=15, CIN=COUT=32.
// Block = 256 threads = 4 waves; block handles 4 queries; wave w owns anchor w
// for GEMM1. GEMM2: A rows = 16 (anchor,query) pairs, split across waves by
// (d-tile, kk-range): 32 MFMA + 32 Wp loads per BLOCK. Cross-wave partial
// reduction through 2KB LDS (aliases nbr32).
// Final (R10 variant, best measured): barrier-3 removed (barrier 2 already
// orders nbr32 reads before red4 writes); Wp B-frags hoisted into registers
// before barrier 1 (latency hide); single merged prep launch.
// Influence weights via cross-MFMA with bf16 hi/lo split (fp32-grade sq).
// x pre-converted to bf16 (4 MB, L2-resident); W pre-permuted to B-frag layout.

typedef short bf16x8 __attribute__((ext_vector_type(8)));
typedef float f32x4  __attribute__((ext_vector_type(4)));

// round-half-up bf16: 2 VALU ops. <=1 ulp vs RNE on ties.
__device__ __forceinline__ unsigned short f2bf(float f) {
    unsigned u = __builtin_bit_cast(unsigned, f);
    return (unsigned short)((u + 0x8000u) >> 16);
}
__device__ __forceinline__ float bf2f(unsigned short h) {
    return __builtin_bit_cast(float, (unsigned)h << 16);
}
// pack two floats -> (bf(hi)<<16)|bf(lo) in 3 VALU ops via v_perm_b32
__device__ __forceinline__ unsigned pack2bf(float hi, float lo) {
    unsigned uh = __builtin_bit_cast(unsigned, hi) + 0x8000u;
    unsigned ul = __builtin_bit_cast(unsigned, lo) + 0x8000u;
    return __builtin_amdgcn_perm(uh, ul, 0x07060302u);
}
// hi/lo split: v ~= bf(h) + bf(l), residual ~2^-18 rel
__device__ __forceinline__ void bfsplit(float v, unsigned short& h, unsigned short& l) {
    h = f2bf(v);
    l = f2bf(v - bf2f(h));
}

// Combined prep: blocks 0..63 build Wp (W permuted to GEMM2 B-frag layout,
// Wp[kk][d][e] = bf16(W[k][c][d]), kcs = kk*32+e = c*16+k, k=15 -> 0);
// blocks 64..1063 convert x (fp32) -> xb (bf16), 8 floats/thread.
__global__ void prep_all(const float* __restrict__ W, unsigned short* __restrict__ Wp,
                         const float* __restrict__ x, unsigned short* __restrict__ xb) {
    const int bid = blockIdx.x;
    if (bid < 64) {
        const int idx = bid * 256 + threadIdx.x;   // 0..16383
        const int kk = idx >> 10, d = (idx >> 5) & 31, e = idx & 31;
        const int kcs = kk * 32 + e;
        const int c = kcs >> 4, k = kcs & 15;
        const float v = (k < 15) ? W[(k * 32 + c) * 32 + d] : 0.0f;
        Wp[idx] = f2bf(v);
    } else {
        const int i = ((bid - 64) * 256 + threadIdx.x) * 8;
        const float4 v0 = *(const float4*)&x[i];
        const float4 v1 = *(const float4*)&x[i + 4];
        uint4 u;
        u.x = pack2bf(v0.y, v0.x); u.y = pack2bf(v0.w, v0.z);
        u.z = pack2bf(v1.y, v1.x); u.w = pack2bf(v1.w, v1.z);
        *(uint4*)&xb[i] = u;
    }
}

__global__ __launch_bounds__(256) void kpconv_mfma(
    const float* __restrict__ q_pts,    // [N,3]
    const float* __restrict__ s_pts,    // [M,3]
    const int*   __restrict__ inds,     // [N,32]
    const unsigned short* __restrict__ xb, // [M,4,32] bf16
    const float* __restrict__ kp,       // [15,3]
    const float* __restrict__ anchors,  // [4,3,3]
    const unsigned short* __restrict__ Wp, // [16][32][32] bf16 (permuted)
    float*       __restrict__ out)      // [N,4,32]
{
    // xa_s: [a][q][c][b_slot] bf16, 32KB; per-a 4KB slice aliased by wf after
    // GEMM1 (wave-private until barrier 2; additive column shift q*16+a*8).
    __shared__ __align__(16) unsigned short xa_s[16384];
    // nbr32: per (q,b) 16-slot bf16 A-row for the cross-MFMA; row stride 24
    // shorts (48B, keeps 16B alignment). 6 KB. Aliased by red4 after barrier 2.
    __shared__ __align__(16) unsigned short nbr32[3072];

    const int t  = threadIdx.x;
    const int n0 = blockIdx.x * 4;
    const int a = t >> 6, lane = t & 63, l15 = lane & 15, quad = lane >> 4;

    // ---- GEMM2 role constants + hoisted Wp B-frags (independent loads) ----
    const int tile = a & 1;            // d-tile (0: d<16, 1: d>=16)
    const int kkb  = (a >> 1) * 8;     // kk-range
    bf16x8 wreg[8];
    #pragma unroll
    for (int kk2 = 0; kk2 < 8; ++kk2) {
        wreg[kk2] = *(const bf16x8*)&Wp[(kkb + kk2) * 1024 + (tile * 16 + l15) * 32 + quad * 8];
    }

    // ---- prologue: per-lane B-frag (constant) for the cross-MFMA ----
    // kdim slots: 0:k2h 1:k2l 2:Rxh 3:Rxl 4:Rxh 5:Ryh 6:Ryl 7:Ryh |
    //             8:Rzh 9:Rzl 10:Rzh 11:1 12:1 13..31:0    (R = -2*r)
    bf16x8 rkb;
    {
        float rx = 0.f, ry = 0.f, rz = 0.f, k2 = 1e30f;   // k=15 sentinel -> w=0
        if (l15 < 15) {
            const float kx = kp[l15*3+0], ky = kp[l15*3+1], kz = kp[l15*3+2];
            const float* R = anchors + a * 9;
            rx = R[0]*kx + R[1]*ky + R[2]*kz;
            ry = R[3]*kx + R[4]*ky + R[5]*kz;
            rz = R[6]*kx + R[7]*ky + R[8]*kz;
            k2 = rx*rx + ry*ry + rz*rz;
        }
        unsigned short k2h,k2l, Rxh,Rxl, Ryh,Ryl, Rzh,Rzl;
        bfsplit(k2, k2h, k2l);
        bfsplit(-2.0f*rx, Rxh, Rxl);
        bfsplit(-2.0f*ry, Ryh, Ryl);
        bfsplit(-2.0f*rz, Rzh, Rzl);
        const unsigned ONE = 0x3F80u;
        uint4 u;
        if (quad == 0) {
            u.x = (unsigned)k2h | ((unsigned)k2l << 16);
            u.y = (unsigned)Rxh | ((unsigned)Rxl << 16);
            u.z = (unsigned)Rxh | ((unsigned)Ryh << 16);
            u.w = (unsigned)Ryl | ((unsigned)Ryh << 16);
        } else if (quad == 1) {
            u.x = (unsigned)Rzh | ((unsigned)Rzl << 16);
            u.y = (unsigned)Rzh | (ONE << 16);
            u.z = ONE;
            u.w = 0u;
        } else {
            u.x = u.y = u.z = u.w = 0u;   // B slots 16..31 zero -> A there don't-care
        }
        rkb = __builtin_bit_cast(bf16x8, u);
    }

    // ---- stage nbr32 A-rows (t<128) ----
    if (t < 128) {
        const int q = t >> 5, b = t & 31;
        const int idx = inds[(n0 + q) * 32 + b];
        const float nx = s_pts[idx*3+0] - q_pts[(n0+q)*3+0];
        const float ny = s_pts[idx*3+1] - q_pts[(n0+q)*3+1];
        const float nz = s_pts[idx*3+2] - q_pts[(n0+q)*3+2];
        const float n2 = nx*nx + ny*ny + nz*nz;
        unsigned short nxh,nxl, nyh,nyl, nzh,nzl, n2h,n2l;
        bfsplit(nx, nxh, nxl); bfsplit(ny, nyh, nyl);
        bfsplit(nz, nzh, nzl); bfsplit(n2, n2h, n2l);
        const unsigned ONE = 0x3F80u;
        // A slots: 0:1 1:1 2:nxh 3:nxh 4:nxl 5:nyh 6:nyh 7:nyl |
        //          8:nzh 9:nzh 10:nzl 11:n2h 12:n2l 13..15:0
        unsigned short* p = &nbr32[(q * 32 + b) * 24];
        *(uint2*)(p)      = make_uint2(ONE | (ONE << 16),
                                       (unsigned)nxh | ((unsigned)nxh << 16));
        *(uint2*)(p + 4)  = make_uint2((unsigned)nxl | ((unsigned)nyh << 16),
                                       (unsigned)nyh | ((unsigned)nyl << 16));
        *(uint2*)(p + 8)  = make_uint2((unsigned)nzh | ((unsigned)nzh << 16),
                                       (unsigned)nzl | ((unsigned)n2h << 16));
        *(uint2*)(p + 12) = make_uint2((unsigned)n2l, 0u);
    }

    // ---- P2: gather xb -> xa_s (register transpose) ----
    // logical b = 4*bg+i -> slot = ((bg&3)^fc)*8 + (bg>>2)*4 + i, fc = c4&3.
    {
        const int c4 = t & 7, bg = (t >> 3) & 7, q = t >> 6;
        const int4 rows = *(const int4*)&inds[(n0 + q) * 32 + 4 * bg];
        const int fcs   = c4 & 3;
        const int slotb = ((bg & 3) ^ fcs) * 8 + (bg >> 2) * 4;
        unsigned short* base = &xa_s[(q * 32) * 32 + slotb];
        #pragma unroll
        for (int aa = 0; aa < 4; ++aa) {
            const uint2 r0 = *(const uint2*)&xb[rows.x * 128 + aa * 32 + c4 * 4];
            const uint2 r1 = *(const uint2*)&xb[rows.y * 128 + aa * 32 + c4 * 4];
            const uint2 r2 = *(const uint2*)&xb[rows.z * 128 + aa * 32 + c4 * 4];
            const uint2 r3 = *(const uint2*)&xb[rows.w * 128 + aa * 32 + c4 * 4];
            unsigned short* pa = base + aa * 4096;
            uint2 w;
            w.x = __builtin_amdgcn_perm(r1.x, r0.x, 0x05040100u);
            w.y = __builtin_amdgcn_perm(r3.x, r2.x, 0x05040100u);
            *(uint2*)&pa[(4 * c4 + 0) * 32] = w;
            w.x = __builtin_amdgcn_perm(r1.x, r0.x, 0x07060302u);
            w.y = __builtin_amdgcn_perm(r3.x, r2.x, 0x07060302u);
            *(uint2*)&pa[(4 * c4 + 1) * 32] = w;
            w.x = __builtin_amdgcn_perm(r1.y, r0.y, 0x05040100u);
            w.y = __builtin_amdgcn_perm(r3.y, r2.y, 0x05040100u);
            *(uint2*)&pa[(4 * c4 + 2) * 32] = w;
            w.x = __builtin_amdgcn_perm(r1.y, r0.y, 0x07060302u);
            w.y = __builtin_amdgcn_perm(r3.y, r2.y, 0x07060302u);
            *(uint2*)&pa[(4 * c4 + 3) * 32] = w;
        }
    }
    __syncthreads();   // barrier 1: xa_s + nbr32 visible

    // ---------------- GEMM1 per wave (anchor a = wave id) ----------------
    const int fc = (l15 >> 2) & 3;
    unsigned short* wfb = &xa_s[a * 4096];
    const f32x4 zacc = {0.f, 0.f, 0.f, 0.f};
    const int S = a * 8;   // + q*16 added per q below (additive column shift)

    #pragma unroll
    for (int q = 0; q < 4; ++q) {
        // cross-MFMA: sq[b][k]; quads 2-3 broadcast quads 0-1 addresses
        // (their B slots are zero -> A values are don't-care).
        const unsigned short* aX = &nbr32[(q * 32 + l15) * 24 + (quad & 1) * 8];
        const unsigned short* aY = &nbr32[(q * 32 + 16 + l15) * 24 + (quad & 1) * 8];
        const f32x4 s0 = __builtin_amdgcn_mfma_f32_16x16x32_bf16(*(const bf16x8*)aX, rkb, zacc, 0, 0, 0);
        const f32x4 s1 = __builtin_amdgcn_mfma_f32_16x16x32_bf16(*(const bf16x8*)aY, rkb, zacc, 0, 0, 0);
        // D: col k = l15, rows b = quad*4+reg (s0), 16+quad*4+reg (s1)
        float w8[8];
        #pragma unroll
        for (int j = 0; j < 4; ++j) {
            w8[j]     = fmaxf(fmaf(sqrtf(fmaxf(s0[j], 1e-12f)), -1.6666667f, 1.0f), 0.0f);
            w8[4 + j] = fmaxf(fmaf(sqrtf(fmaxf(s1[j], 1e-12f)), -1.6666667f, 1.0f), 0.0f);
        }
        uint4 uu;
        uu.x = pack2bf(w8[1], w8[0]); uu.y = pack2bf(w8[3], w8[2]);
        uu.z = pack2bf(w8[5], w8[4]); uu.w = pack2bf(w8[7], w8[6]);
        const bf16x8 afr = __builtin_bit_cast(bf16x8, uu);   // A[k=l15][b-octet(quad)]

        // GEMM1: B[b][c] from xa (slot-permuted to match), D: col c, rows k.
        const bf16x8 b0 = *(const bf16x8*)&xa_s[((a*4 + q)*32 + l15)      * 32 + 8 * (quad ^ fc)];
        const bf16x8 b1 = *(const bf16x8*)&xa_s[((a*4 + q)*32 + l15 + 16) * 32 + 8 * (quad ^ fc)];
        f32x4 d0 = zacc, d1 = zacc;
        d0 = __builtin_amdgcn_mfma_f32_16x16x32_bf16(afr, b0, d0, 0, 0, 0);
        d1 = __builtin_amdgcn_mfma_f32_16x16x32_bf16(afr, b1, d1, 0, 0, 0);
        // wf store: row q, column (kcs + q*16 + a*8) & 511, kcs = c*16 + k
        uint2 s0p, s1p;
        s0p.x = pack2bf(d0[1], d0[0]); s0p.y = pack2bf(d0[3], d0[2]);
        s1p.x = pack2bf(d1[1], d1[0]); s1p.y = pack2bf(d1[3], d1[2]);
        const int Sq = S + q * 16;
        *(uint2*)&wfb[q*512 + ((l15*16       + quad*4 + Sq) & 511)] = s0p;
        *(uint2*)&wfb[q*512 + ((l15*16 + 256 + quad*4 + Sq) & 511)] = s1p;
    }
    __syncthreads();   // barrier 2: all wf visible; also orders nbr32 reads
                       // before the red4 writes below (no extra barrier needed)

    // ---------------- GEMM2 (block-wide, split across waves) ----------------
    // A rows m = a_src*4 + q (16 rows); wave w: d-tile = w&1, kk-range (w>>1)*8.
    const int a_src = l15 >> 2, qv = l15 & 3;
    const unsigned short* abase = &xa_s[a_src * 4096 + qv * 512];
    const int shf = qv * 16 + a_src * 8;
    f32x4 o = zacc;
    #pragma unroll
    for (int kk2 = 0; kk2 < 8; ++kk2) {
        const bf16x8 a2 = *(const bf16x8*)&abase[((kkb + kk2)*32 + quad*8 + shf) & 511];
        o = __builtin_amdgcn_mfma_f32_16x16x32_bf16(a2, wreg[kk2], o, 0, 0, 0);
    }
    // red4 aliases nbr32 — safe: all nbr32 reads were before barrier 2.
    float4* red4 = (float4*)nbr32;   // 2 KB used
    if (a >= 2) {
        red4[(a - 2) * 64 + lane] = make_float4(o[0], o[1], o[2], o[3]);
    }
    __syncthreads();   // partials visible
    if (a < 2) {
        const float4 p = red4[a * 64 + lane];
        o[0] += p.x; o[1] += p.y; o[2] += p.z; o[3] += p.w;
        // D rows m = quad*4+reg -> (a_out = quad, q_out = reg); col d = tile*16+l15
        #pragma unroll
        for (int r = 0; r < 4; ++r) {
            out[((n0 + r) * 4 + quad) * 32 + tile * 16 + l15] = o[r];
        }
    }
}

extern "C" void kernel_launch(void* const* d_in, const int* in_sizes, int n_in,
                              void* d_out, int out_size, void* d_ws, size_t ws_size,
                              hipStream_t stream) {
    const float* q_pts   = (const float*)d_in[0];
    const float* s_pts   = (const float*)d_in[1];
    const int*   inds    = (const int*)d_in[2];
    const float* x       = (const float*)d_in[3];
    const float* kp      = (const float*)d_in[4];
    const float* anchors = (const float*)d_in[5];
    const float* weights = (const float*)d_in[6];
    float*       out     = (float*)d_out;

    unsigned short* Wp = (unsigned short*)d_ws;                       // 32 KB
    unsigned short* xb = (unsigned short*)((char*)d_ws + (1 << 16));  // 4 MB

    prep_all<<<dim3(1064), dim3(256), 0, stream>>>(weights, Wp, x, xb);
    kpconv_mfma<<<dim3(4000), dim3(256), 0, stream>>>(
        q_pts, s_pts, inds, xb, kp, anchors, Wp, out);
}